// Round 4
// baseline (893.794 us; speedup 1.0000x reference)
//
#include <hip/hip_runtime.h>

// HybridMambaBlock pipeline:
//  1) cvt: W_res/W_out f32 -> bf16 (W_in is now consumed as f32 by gemm256)
//  2) ln: LayerNorm(x) -> xn(bf16); also x -> bf16 for the residual GEMM
//  3) gemm256_bt: p = xn @ W_in^T (2048 x 52480) -- 256^2 8-phase schedule,
//     B staged f32->scratch-LDS->cvt->bf16 in-kernel (cvt pass eliminated)
//  4) gemm_bt<f32 out>:  res = x @ W_res^T
//  5) dt: dt = clip(softplus(dth @ W_dt^T + bias), 1e-4, 1)
//  6) scan v3: chunk-parallel (P=64), lane-owns-d; depthwise conv K=4 fused
//     inline (conv_kernel + ucv round-trip eliminated; bit-identical math)
//  7) gate: g = rmsnorm(y*silu(z))*norm_w + res -> bf16
//  8) gemm_bt<f32 out>: out = g @ W_out^T
//
// R9:
//  - gemm256: B from W_in f32 directly. Staging = global_load_lds (f32,
//    quarter-slots, 2x16KB scratch @128KB..160KB) -> vmcnt-counted -> cvt
//    (same f2bf rounding => bit-identical p) -> ds_write into the EXACT bf16
//    layout R8's read side expects (read path untouched, conflicts stay 0).
//    All staging ops are intrinsics/volatile-asm => program-ordered, so the
//    static vmcnt counts hold: uniform vmcnt(2) at even phases, vmcnt(4) at
//    odd phases; quarter staged at phase p is cvt'd at p+2; scratch slot
//    reissue happens AFTER its cvt-read in program order (no WAR).
//  - scan1/scan2: conv fused (cw[4],cb regs + 3-reg history; same fmaf order
//    and zero-guard semantics as conv_kernel => bit-identical y).

typedef unsigned short u16;
typedef __bf16 bf16x8 __attribute__((ext_vector_type(8)));
typedef float f32x4 __attribute__((ext_vector_type(4)));

#define OPAD 52480   // 205*256 >= 52272 ; row stride of p
#define OTOT 52272
#define DI   1536
#define DM   768
#define Z0   0
#define U0   1536
#define DTH0 3072
#define B0   3120
#define C0   27696

#define SCAN_P 64
#define SCAN_T 16    // 1024 / SCAN_P
#define SPF    4     // prefetch ring depth (must divide SCAN_T)

__device__ static inline u16 f2bf(float f) {
    unsigned u = __float_as_uint(f);
    u += 0x7fffu + ((u >> 16) & 1u);
    return (u16)(u >> 16);
}
__device__ static inline float bf2f(u16 s) {
    return __uint_as_float(((unsigned)s) << 16);
}
__device__ static inline unsigned pack2(float lo, float hi) {
    return (unsigned)f2bf(lo) | ((unsigned)f2bf(hi) << 16);
}

__device__ static inline void gload16(const void* g, void* l) {
    __builtin_amdgcn_global_load_lds(
        (const __attribute__((address_space(1))) unsigned int*)g,
        (__attribute__((address_space(3))) unsigned int*)l, 16, 0, 0);
}

// unpack 8 bf16 (as uint4) -> 8 f32, memory order preserved
__device__ static inline void unpack8(uint4 v, float* f) {
    unsigned w0 = v.x, w1 = v.y, w2 = v.z, w3 = v.w;
    f[0] = __uint_as_float(w0 << 16); f[1] = __uint_as_float(w0 & 0xffff0000u);
    f[2] = __uint_as_float(w1 << 16); f[3] = __uint_as_float(w1 & 0xffff0000u);
    f[4] = __uint_as_float(w2 << 16); f[5] = __uint_as_float(w2 & 0xffff0000u);
    f[6] = __uint_as_float(w3 << 16); f[7] = __uint_as_float(w3 & 0xffff0000u);
}

// ---------------- f32 -> bf16 convert (with zero pad to n_tot) ----------------
__global__ void cvt_kernel(const float* __restrict__ src, u16* __restrict__ dst,
                           long n_src, long n_tot) {
    long i4 = ((long)blockIdx.x * 256 + threadIdx.x) * 4;
    if (i4 >= n_tot) return;
    ushort4 o;
    if (i4 < n_src) {
        float4 v = *(const float4*)(src + i4);
        o.x = f2bf(v.x); o.y = f2bf(v.y); o.z = f2bf(v.z); o.w = f2bf(v.w);
    } else {
        o.x = o.y = o.z = o.w = 0;
    }
    *(ushort4*)(dst + i4) = o;
}

// ---------------- block reduce (sum of two values across 256 threads) --------
__device__ static inline void block_reduce2(float& a, float& b) {
    #pragma unroll
    for (int o = 32; o > 0; o >>= 1) {
        a += __shfl_down(a, o);
        b += __shfl_down(b, o);
    }
    __shared__ float sa[4], sb[4];
    int lane = threadIdx.x & 63, w = threadIdx.x >> 6;
    if (lane == 0) { sa[w] = a; sb[w] = b; }
    __syncthreads();
    a = sa[0] + sa[1] + sa[2] + sa[3];
    b = sb[0] + sb[1] + sb[2] + sb[3];
}

// ---------------- LayerNorm -> xn bf16, plus raw x -> bf16 -------------------
__global__ void __launch_bounds__(256) ln_kernel(const float* __restrict__ x,
        const float* __restrict__ w, const float* __restrict__ b,
        u16* __restrict__ xnbf, u16* __restrict__ xbf) {
    int m = blockIdx.x, tid = threadIdx.x;
    const float* xr = x + (size_t)m * DM;
    float v[3];
    v[0] = xr[tid]; v[1] = xr[tid + 256]; v[2] = xr[tid + 512];
    float s = v[0] + v[1] + v[2];
    float ss = v[0]*v[0] + v[1]*v[1] + v[2]*v[2];
    block_reduce2(s, ss);
    float mu = s * (1.f / DM);
    float var = ss * (1.f / DM) - mu * mu;
    float inv = rsqrtf(var + 1e-5f);
    #pragma unroll
    for (int i = 0; i < 3; ++i) {
        int d = tid + i * 256;
        float xn = (v[i] - mu) * inv * w[d] + b[d];
        xnbf[(size_t)m * DM + d] = f2bf(xn);
        xbf[(size_t)m * DM + d] = f2bf(v[i]);
    }
}

// ---------------- bf16 MFMA GEMM: C[M,N] = A[M,K] * B[N,K]^T -----------------
// 128x128 tile, BK=64, 256 threads. Used for the two small GEMMs (res, out).
template <int OUT_BF16>
__global__ void __launch_bounds__(256) gemm_bt(const u16* __restrict__ A,
        const u16* __restrict__ B, void* __restrict__ C, int K, int ldc) {
    __shared__ u16 smem[2 * 128 * 64];
    u16* As = smem;
    u16* Bs = smem + 128 * 64;
    int tid = threadIdx.x;
    int m0 = blockIdx.x * 128, n0 = blockIdx.y * 128;
    int lane = tid & 63, wave = tid >> 6;
    int wm = wave >> 1, wn = wave & 1;
    int l15 = lane & 15, l4 = lane >> 4;
    f32x4 acc[4][4] = {};
    const u16* Ag = A + (size_t)m0 * K;
    const u16* Bg = B + (size_t)n0 * K;
    int crow = tid >> 3;
    int ccol = ((tid & 7) ^ ((tid >> 3) & 7)) * 8;
    int ldsoff = (tid & 192) * 16;
    int xr = l15 & 7;

    for (int k0 = 0; k0 < K; k0 += 64) {
        __syncthreads();
        #pragma unroll
        for (int it = 0; it < 4; ++it) {
            gload16(Ag + (size_t)(it * 32 + crow) * K + k0 + ccol,
                    (char*)As + it * 4096 + ldsoff);
            gload16(Bg + (size_t)(it * 32 + crow) * K + k0 + ccol,
                    (char*)Bs + it * 4096 + ldsoff);
        }
        __syncthreads();
        const u16* Arow = As + (wm * 64 + l15) * 64;
        const u16* Brow = Bs + (wn * 64 + l15) * 64;
        #pragma unroll
        for (int kk8 = 0; kk8 < 8; kk8 += 4) {
            int sw = ((l4 + kk8) ^ xr) * 8;
            bf16x8 af[4], bfr[4];
            #pragma unroll
            for (int i = 0; i < 4; ++i) af[i] = *(const bf16x8*)(Arow + i * 16 * 64 + sw);
            #pragma unroll
            for (int j = 0; j < 4; ++j) bfr[j] = *(const bf16x8*)(Brow + j * 16 * 64 + sw);
            #pragma unroll
            for (int i = 0; i < 4; ++i)
                #pragma unroll
                for (int j = 0; j < 4; ++j)
                    acc[i][j] = __builtin_amdgcn_mfma_f32_16x16x32_bf16(
                        af[i], bfr[j], acc[i][j], 0, 0, 0);
        }
    }
    #pragma unroll
    for (int i = 0; i < 4; ++i) {
        int row = m0 + wm * 64 + i * 16 + l4 * 4;
        #pragma unroll
        for (int j = 0; j < 4; ++j) {
            int col = n0 + wn * 64 + j * 16 + l15;
            #pragma unroll
            for (int r = 0; r < 4; ++r) {
                size_t off = (size_t)(row + r) * ldc + col;
                if (OUT_BF16) ((u16*)C)[off] = f2bf(acc[i][j][r]);
                else          ((float*)C)[off] = acc[i][j][r];
            }
        }
    }
}

// ---------------- 256x256 8-phase bf16 GEMM (the big GEMM) -------------------
// C[M,N](bf16) = A[M,K](bf16) * B[N,K](f32)^T. 512 threads (8 waves, 2Mx4N),
// BK=64. LDS 160 KiB: 128 KiB double-buffered bf16 tiles (R8 packed row-pair
// layout, read side unchanged) + 32 KiB f32 staging scratch (2 slots).
// Per phase p: vmcnt(2|4) -> cvt+write quarter staged at p-2 -> A-stage (even
// phases) + B-quarter f32 gload_lds into scratch slot (p&1) -> ds_reads ->
// lgkm(0) -> barrier -> setprio(1) 16 MFMA setprio(0) -> barrier.
#define G2_BUF  65536
#define G2_HALF 16384
#define G2_BOFF 32768
#define G2_SCR  131072

__global__ void __launch_bounds__(512, 2) gemm256_bt(const u16* __restrict__ A,
        const float* __restrict__ B, u16* __restrict__ C, int K, int ldc) {
    __shared__ u16 smem[81920];           // 160 KiB
    char* smemc = (char*)smem;
    const int tid = threadIdx.x;
    const int l = tid & 63, w = tid >> 6;          // lane, wave 0..7
    const int wm = w >> 2, wn = w & 3;             // 2 x 4 wave grid
    const int l15 = l & 15, l4 = l >> 4;
    // XCD-aware bijective remap (grid is exactly 8 x 205 = 1640 blocks).
    const int flat = blockIdx.y * 8 + blockIdx.x;
    const int wg = (flat & 7) * 205 + (flat >> 3);
    const int m0 = (wg & 7) * 256, n0 = (wg >> 3) * 256;
    const int NT = K >> 6;                         // K-tiles of 64 (even)

    // read side (unchanged from R8): packed row-pair layout
    const int rA = l15 >> 1;
    const int rdoff = rA * 128 + ((((l4 << 1) + (l15 & 1)) ^ ((rA & 3) << 1)) << 4);
    // stage side
    const int wpr = (l & 7) ^ (((l >> 3) & 3) << 1);
    const int srow = w * 32 + ((l >> 3) << 1) + (wpr & 1);
    const u16* Ast = A + (size_t)(m0 + srow) * K + (wpr >> 1) * 8;
    const int nrow0 = n0 + srow, nrow1 = nrow0 + 16;
    const int oobA = nrow0 >= OTOT, oobB = nrow1 >= OTOT;
    const float* Bf0 = B + (size_t)(oobA ? 0 : nrow0) * K + (wpr >> 1) * 8;
    const float* Bf1 = B + (size_t)(oobB ? 0 : nrow1) * K + (wpr >> 1) * 8;
    const int sdst = w * 2048;                     // wave-uniform LDS dest

    f32x4 acc[8][4] = {};
    bf16x8 bvK[4];                                 // live across rh0/rh1 pair

#define G2_ASTAGE(nxt, sh, tk)                                                 \
    gload16(Ast + (size_t)(tk) * 64 + (sh) * 32,                               \
            smemc + (nxt) * G2_BUF + (sh) * G2_HALF + sdst);                   \
    gload16(Ast + (size_t)16 * K + (size_t)(tk) * 64 + (sh) * 32,              \
            smemc + (nxt) * G2_BUF + (sh) * G2_HALF + sdst + 1024);

// issue B-quarter (rows set qc, K-half qh) of tile tk into scratch slot QS
#define G2_BISSUE(QS, qh, qc, tk)                                              \
    {   const float* bq = ((qc) ? Bf1 : Bf0) + (size_t)(tk) * 64 + (qh) * 32;  \
        gload16(bq,     smemc + G2_SCR + (QS) * 16384 + sdst);                 \
        gload16(bq + 4, smemc + G2_SCR + (QS) * 16384 + sdst + 1024); }

// cvt scratch slot QS -> bf16 quarter (buffer wbuf, half wh, chunk wc)
#define G2_BCVT(QS, wbuf, wh, wc)                                              \
    {   const char* scr = smemc + G2_SCR + (QS) * 16384 + sdst + l * 16;       \
        f32x4 flo = *(const f32x4*)scr;                                        \
        f32x4 fhi = *(const f32x4*)(scr + 1024);                               \
        uint4 ov;                                                              \
        ov.x = pack2(flo[0], flo[1]); ov.y = pack2(flo[2], flo[3]);            \
        ov.z = pack2(fhi[0], fhi[1]); ov.w = pack2(fhi[2], fhi[3]);            \
        if ((wc) ? oobB : oobA) ov = make_uint4(0, 0, 0, 0);                   \
        *(uint4*)(smemc + (wbuf) * G2_BUF + G2_BOFF + (wh) * G2_HALF           \
                  + sdst + (wc) * 1024 + l * 16) = ov; }

#define G2_PH(cur, nxt, rh, h, ASTG, QS, qh, qc, tk, DOW, wbuf, wh, wc, VN)    \
    {                                                                          \
        asm volatile("s_waitcnt vmcnt(" #VN ")" ::: "memory");                 \
        if (DOW) { G2_BCVT(QS, wbuf, wh, wc) }                                 \
        if (ASTG) { G2_ASTAGE(nxt, h, tk) }                                    \
        G2_BISSUE(QS, qh, qc, tk)                                              \
        const char* Ab = smemc + (cur) * G2_BUF + (h) * G2_HALF                \
                         + (wm * 128 + (rh) * 64) * 64 + rdoff;                \
        bf16x8 af[4];                                                          \
        if (!(rh)) {                                                           \
            const char* Bb = smemc + (cur) * G2_BUF + G2_BOFF + (h) * G2_HALF  \
                             + (wn * 64) * 64 + rdoff;                         \
            _Pragma("unroll") for (int j = 0; j < 4; ++j)                      \
                bvK[j] = *(const bf16x8*)(Bb + j * 1024);                      \
        }                                                                      \
        _Pragma("unroll") for (int i = 0; i < 4; ++i)                          \
            af[i] = *(const bf16x8*)(Ab + i * 1024);                           \
        asm volatile("s_waitcnt lgkmcnt(0)" ::: "memory");                     \
        __builtin_amdgcn_s_barrier();                                          \
        __builtin_amdgcn_s_setprio(1);                                         \
        _Pragma("unroll") for (int i = 0; i < 4; ++i)                          \
            _Pragma("unroll") for (int j = 0; j < 4; ++j)                      \
                acc[(rh) * 4 + i][j] = __builtin_amdgcn_mfma_f32_16x16x32_bf16(\
                    af[i], bvK[j], acc[(rh) * 4 + i][j], 0, 0, 0);             \
        __builtin_amdgcn_s_setprio(0);                                         \
        __builtin_amdgcn_s_barrier();                                          \
    }

// tile: consume cur; stage tile tk into nxt. Quarters of tk staged at
// ph0..ph3 (slots 0,1,0,1); q0/q1 cvt'd at ph2/ph3 (-> nxt h0); q2/q3 cvt'd
// at next tile's ph0/ph1 (-> its cur h1). W01=0 skips ph0/ph1 writes (peel).
#define G2_TILE(cur, nxt, tk, W01)                                             \
    G2_PH(cur, nxt, 0, 0, 1, 0, 0, 0, tk, W01, cur, 1, 0, 2)                   \
    G2_PH(cur, nxt, 1, 0, 0, 1, 0, 1, tk, W01, cur, 1, 1, 4)                   \
    G2_PH(cur, nxt, 0, 1, 1, 0, 1, 0, tk, 1,   nxt, 0, 0, 2)                   \
    G2_PH(cur, nxt, 1, 1, 0, 1, 1, 1, tk, 1,   nxt, 0, 1, 4)

    // prologue: stage tile 0 fully into buffer 0
    G2_ASTAGE(0, 0, 0);                                   // +2
    G2_ASTAGE(0, 1, 0);                                   // +2
    G2_BISSUE(0, 0, 0, 0)                                 // q0 -> slot0  +2
    G2_BISSUE(1, 0, 1, 0)                                 // q1 -> slot1  +2
    asm volatile("s_waitcnt vmcnt(2)" ::: "memory");      // A + q0 landed
    G2_BCVT(0, 0, 0, 0)                                   // q0 -> buf0 h0 c0
    G2_BISSUE(0, 1, 0, 0)                                 // q2 -> slot0  +2
    asm volatile("s_waitcnt vmcnt(2)" ::: "memory");      // q1 landed
    G2_BCVT(1, 0, 0, 1)                                   // q1 -> buf0 h0 c1
    G2_BISSUE(1, 1, 1, 0)                                 // q3 -> slot1  +2
    asm volatile("s_waitcnt vmcnt(2)" ::: "memory");      // q2 landed
    G2_BCVT(0, 0, 1, 0)                                   // q2 -> buf0 h1 c0
    asm volatile("s_waitcnt vmcnt(0)" ::: "memory");      // q3 landed
    G2_BCVT(1, 0, 1, 1)                                   // q3 -> buf0 h1 c1
    asm volatile("s_waitcnt lgkmcnt(0)" ::: "memory");
    __builtin_amdgcn_s_barrier();

    // peel: consume tile 0, stage tile 1 (its q2/q3 written by tile-1 ph0/ph1)
    G2_TILE(0, 1, 1, 0)
    for (int t = 1; t + 1 < NT; t += 2) {
        G2_TILE(1, 0, t + 1, 1)
        G2_TILE(0, 1, (t + 2 < NT ? t + 2 : NT - 1), 1)
    }
    G2_TILE(1, 0, NT - 1, 1)   // consume tile NT-1 (harmless self-restage)

    #pragma unroll
    for (int ai = 0; ai < 8; ++ai) {
        int row = m0 + wm * 128 + ai * 16 + l4 * 4;
        #pragma unroll
        for (int j = 0; j < 4; ++j) {
            int col = n0 + wn * 64 + j * 16 + l15;
            #pragma unroll
            for (int r = 0; r < 4; ++r)
                C[(size_t)(row + r) * ldc + col] = f2bf(acc[ai][j][r]);
        }
    }
#undef G2_ASTAGE
#undef G2_BISSUE
#undef G2_BCVT
#undef G2_PH
#undef G2_TILE
}

// ---------------- dt = clip(softplus(dth @ W_dt^T + bias)) -------------------
__global__ void __launch_bounds__(256) dt_kernel(const u16* __restrict__ p,
        const float* __restrict__ Wdt, const float* __restrict__ dt_bias,
        float* __restrict__ dt) {
    int m0 = blockIdx.x * 16, tid = threadIdx.x;
    __shared__ float dth_s[16 * 48];
    for (int i = tid; i < 16 * 48; i += 256)
        dth_s[i] = bf2f(p[(size_t)(m0 + i / 48) * OPAD + DTH0 + (i % 48)]);
    __syncthreads();
    #pragma unroll
    for (int ii = 0; ii < 6; ++ii) {
        int d = ii * 256 + tid;
        float base = dt_bias[d];
        float acc[16];
        #pragma unroll
        for (int mm = 0; mm < 16; ++mm) acc[mm] = base;
        for (int r = 0; r < 48; ++r) {
            float wv = Wdt[d * 48 + r];
            #pragma unroll
            for (int mm = 0; mm < 16; ++mm)
                acc[mm] = fmaf(wv, dth_s[mm * 48 + r], acc[mm]);
        }
        #pragma unroll
        for (int mm = 0; mm < 16; ++mm) {
            float xv = acc[mm];
            float sp = xv > 20.f ? xv : log1pf(__expf(xv));
            sp = fminf(fmaxf(sp, 1e-4f), 1.0f);
            dt[(size_t)(m0 + mm) * DI + d] = sp;
        }
    }
}

// ---------------- scan v3 pass 1: per-chunk (A,h) summaries, conv fused ------
__global__ void __launch_bounds__(256, 2) scan1_kernel(const u16* __restrict__ p,
        const float* __restrict__ dt, const float* __restrict__ A_log,
        const float* __restrict__ cw, const float* __restrict__ cb,
        float* __restrict__ chkA, float* __restrict__ chkB) {
    int d = blockIdx.x * 256 + threadIdx.x;
    int b = blockIdx.y, c = blockIdx.z;
    int t0base = c * SCAN_T;
    float a[16];
    #pragma unroll
    for (int n = 0; n < 16; ++n) a[n] = -__expf(A_log[d * 16 + n]);
    float cw0 = cw[d*4], cw1 = cw[d*4+1], cw2 = cw[d*4+2], cw3 = cw[d*4+3];
    float cbv = cb[d];
    const u16* pB = p + (size_t)(b * 1024 + t0base) * OPAD + B0 + d * 16;
    const u16* pU = p + (size_t)(b * 1024 + t0base) * OPAD + U0 + d;
    const float* dtp = dt + (size_t)(b * 1024 + t0base) * DI + d;
    float x1, x2, x3;  // u-raw history x[t-1], x[t-2], x[t-3]
    if (c == 0) { x1 = x2 = x3 = 0.f; }
    else {
        x1 = bf2f(*(pU - (long)OPAD));
        x2 = bf2f(*(pU - 2L * OPAD));
        x3 = bf2f(*(pU - 3L * OPAD));
    }
    uint4 Br[SPF][2]; float dtr[SPF], xur[SPF];
    #pragma unroll
    for (int i = 0; i < SPF; ++i) {
        Br[i][0] = *(const uint4*)(pB + (size_t)i * OPAD);
        Br[i][1] = *(const uint4*)(pB + (size_t)i * OPAD + 8);
        dtr[i] = dtp[(size_t)i * DI];
        xur[i] = bf2f(pU[(size_t)i * OPAD]);
    }
    float h[16], Av[16];
    #pragma unroll
    for (int n = 0; n < 16; ++n) { h[n] = 0.f; Av[n] = 1.f; }
    for (int t0 = 0; t0 < SCAN_T; t0 += SPF) {
        #pragma unroll
        for (int s = 0; s < SPF; ++s) {
            int t = t0 + s;
            uint4 b0 = Br[s][0], b1 = Br[s][1];
            float dtv = dtr[s], xt = xur[s];
            int tl = t + SPF < SCAN_T ? t + SPF : SCAN_T - 1;
            Br[s][0] = *(const uint4*)(pB + (size_t)tl * OPAD);
            Br[s][1] = *(const uint4*)(pB + (size_t)tl * OPAD + 8);
            dtr[s] = dtp[(size_t)tl * DI];
            xur[s] = bf2f(pU[(size_t)tl * OPAD]);
            float uv = cbv;
            uv = fmaf(cw0, x3, uv);
            uv = fmaf(cw1, x2, uv);
            uv = fmaf(cw2, x1, uv);
            uv = fmaf(cw3, xt, uv);
            x3 = x2; x2 = x1; x1 = xt;
            float Bf[16];
            unpack8(b0, Bf); unpack8(b1, Bf + 8);
            float dtu = dtv * uv;
            #pragma unroll
            for (int n = 0; n < 16; ++n) {
                float dA = __expf(dtv * a[n]);
                h[n] = fmaf(dA, h[n], dtu * Bf[n]);
                Av[n] *= dA;
            }
        }
    }
    size_t o = (((size_t)c * 2 + b) * 1536 + d) * 16;
    #pragma unroll
    for (int k = 0; k < 4; ++k) {
        *(float4*)(chkA + o + k * 4) = make_float4(Av[4*k], Av[4*k+1], Av[4*k+2], Av[4*k+3]);
        *(float4*)(chkB + o + k * 4) = make_float4(h[4*k], h[4*k+1], h[4*k+2], h[4*k+3]);
    }
}

// ---------------- scan v3 pass 2: fold chunk summaries -> h_start ------------
__global__ void __launch_bounds__(256) scan_comb_kernel(const float* __restrict__ chkA,
        const float* __restrict__ chkB, float* __restrict__ hstart) {
    int idx = blockIdx.x * 256 + threadIdx.x;  // b*24576 + d*16 + n
    float hs = 0.f;
    for (int c = 0; c < SCAN_P; ++c) {
        size_t o = (size_t)c * 49152 + idx;
        hstart[o] = hs;
        hs = fmaf(chkA[o], hs, chkB[o]);
    }
}

// ---------------- scan v3 pass 3: replay with h_start, emit y; conv fused ----
__global__ void __launch_bounds__(256, 2) scan2_kernel(const u16* __restrict__ p,
        const float* __restrict__ dt, const float* __restrict__ A_log,
        const float* __restrict__ cw, const float* __restrict__ cb,
        const float* __restrict__ Dskip,
        const float* __restrict__ hstart, float* __restrict__ y) {
    int d = blockIdx.x * 256 + threadIdx.x;
    int b = blockIdx.y, c = blockIdx.z;
    int t0base = c * SCAN_T;
    float a[16];
    #pragma unroll
    for (int n = 0; n < 16; ++n) a[n] = -__expf(A_log[d * 16 + n]);
    float Dsk = Dskip[d];
    float cw0 = cw[d*4], cw1 = cw[d*4+1], cw2 = cw[d*4+2], cw3 = cw[d*4+3];
    float cbv = cb[d];
    const u16* pB = p + (size_t)(b * 1024 + t0base) * OPAD + B0 + d * 16;
    const u16* pC = p + (size_t)(b * 1024 + t0base) * OPAD + C0 + d * 16;
    const u16* pU = p + (size_t)(b * 1024 + t0base) * OPAD + U0 + d;
    const float* dtp = dt + (size_t)(b * 1024 + t0base) * DI + d;
    float* yp        = y  + (size_t)(b * 1024 + t0base) * DI + d;
    float x1, x2, x3;
    if (c == 0) { x1 = x2 = x3 = 0.f; }
    else {
        x1 = bf2f(*(pU - (long)OPAD));
        x2 = bf2f(*(pU - 2L * OPAD));
        x3 = bf2f(*(pU - 3L * OPAD));
    }
    uint4 Br[SPF][2], Cr[SPF][2]; float dtr[SPF], xur[SPF];
    #pragma unroll
    for (int i = 0; i < SPF; ++i) {
        Br[i][0] = *(const uint4*)(pB + (size_t)i * OPAD);
        Br[i][1] = *(const uint4*)(pB + (size_t)i * OPAD + 8);
        Cr[i][0] = *(const uint4*)(pC + (size_t)i * OPAD);
        Cr[i][1] = *(const uint4*)(pC + (size_t)i * OPAD + 8);
        dtr[i] = dtp[(size_t)i * DI];
        xur[i] = bf2f(pU[(size_t)i * OPAD]);
    }
    float h[16];
    {
        size_t o = ((size_t)c * 3072 + (size_t)b * 1536 + d) * 16;
        #pragma unroll
        for (int k = 0; k < 4; ++k) {
            float4 hv = *(const float4*)(hstart + o + k * 4);
            h[4*k] = hv.x; h[4*k+1] = hv.y; h[4*k+2] = hv.z; h[4*k+3] = hv.w;
        }
    }
    for (int t0 = 0; t0 < SCAN_T; t0 += SPF) {
        #pragma unroll
        for (int s = 0; s < SPF; ++s) {
            int t = t0 + s;
            uint4 b0 = Br[s][0], b1 = Br[s][1], c0 = Cr[s][0], c1 = Cr[s][1];
            float dtv = dtr[s], xt = xur[s];
            int tl = t + SPF < SCAN_T ? t + SPF : SCAN_T - 1;
            Br[s][0] = *(const uint4*)(pB + (size_t)tl * OPAD);
            Br[s][1] = *(const uint4*)(pB + (size_t)tl * OPAD + 8);
            Cr[s][0] = *(const uint4*)(pC + (size_t)tl * OPAD);
            Cr[s][1] = *(const uint4*)(pC + (size_t)tl * OPAD + 8);
            dtr[s] = dtp[(size_t)tl * DI];
            xur[s] = bf2f(pU[(size_t)tl * OPAD]);
            float uv = cbv;
            uv = fmaf(cw0, x3, uv);
            uv = fmaf(cw1, x2, uv);
            uv = fmaf(cw2, x1, uv);
            uv = fmaf(cw3, xt, uv);
            x3 = x2; x2 = x1; x1 = xt;
            float Bf[16], Cf[16];
            unpack8(b0, Bf); unpack8(b1, Bf + 8);
            unpack8(c0, Cf); unpack8(c1, Cf + 8);
            float dtu = dtv * uv;
            #pragma unroll
            for (int n = 0; n < 16; ++n) {
                float dA = __expf(dtv * a[n]);
                h[n] = fmaf(dA, h[n], dtu * Bf[n]);
            }
            float a0 = fmaf(Cf[0], h[0], uv * Dsk), a1 = Cf[1] * h[1];
            float a2 = Cf[2] * h[2], a3 = Cf[3] * h[3];
            #pragma unroll
            for (int n = 4; n < 16; n += 4) {
                a0 = fmaf(Cf[n],   h[n],   a0);
                a1 = fmaf(Cf[n+1], h[n+1], a1);
                a2 = fmaf(Cf[n+2], h[n+2], a2);
                a3 = fmaf(Cf[n+3], h[n+3], a3);
            }
            yp[(size_t)t * DI] = (a0 + a1) + (a2 + a3);
        }
    }
}

// ---------------- gating + RMSNorm + residual -> g (bf16) --------------------
__global__ void __launch_bounds__(256) gate_kernel(const u16* __restrict__ p,
        const float* __restrict__ y, const float* __restrict__ res,
        const float* __restrict__ norm_w, u16* __restrict__ g) {
    int m = blockIdx.x, tid = threadIdx.x;
    const u16* pz = p + (size_t)m * OPAD + Z0;
    const float* yr = y + (size_t)m * DI;
    float gp[6];
    float ss = 0.f, dummy = 0.f;
    #pragma unroll
    for (int i = 0; i < 6; ++i) {
        int d = i * 256 + tid;
        float z = bf2f(pz[d]);
        float gv = yr[d] * z / (1.f + __expf(-z));
        gp[i] = gv;
        ss += gv * gv;
    }
    block_reduce2(ss, dummy);
    float scale = rsqrtf(ss * (1.f / DI) + 1e-6f);
    #pragma unroll
    for (int i = 0; i < 6; ++i) {
        int d = i * 256 + tid;
        float val = gp[i] * scale * norm_w[d] + res[(size_t)m * DI + d];
        g[(size_t)m * DI + d] = f2bf(val);
    }
}

// ---------------- host ----------------
extern "C" void kernel_launch(void* const* d_in, const int* in_sizes, int n_in,
                              void* d_out, int out_size, void* d_ws, size_t ws_size,
                              hipStream_t stream) {
    const float* x       = (const float*)d_in[0];
    const float* ln_w    = (const float*)d_in[1];
    const float* ln_b    = (const float*)d_in[2];
    const float* W_in    = (const float*)d_in[3];
    const float* W_dt    = (const float*)d_in[4];
    const float* conv_w  = (const float*)d_in[5];
    const float* conv_b  = (const float*)d_in[6];
    const float* A_log   = (const float*)d_in[7];
    const float* Dskip   = (const float*)d_in[8];
    const float* dt_bias = (const float*)d_in[9];
    const float* norm_w  = (const float*)d_in[10];
    const float* W_res   = (const float*)d_in[11];
    const float* W_out   = (const float*)d_in[12];
    float* out = (float*)d_out;

    char* wsb = (char*)d_ws;
    // region [0, 80.6MB) formerly Wbf -- now scan chunk buffers only
    u16* Wresbf  = (u16*)(wsb + 80609280);    //   2,359,296
    u16* Woutbf  = (u16*)(wsb + 82968576);    //   2,359,296
    u16* xnbf    = (u16*)(wsb + 85327872);    //   3,145,728
    u16* xbf     = (u16*)(wsb + 88473600);    //   3,145,728
    u16* pbuf    = (u16*)(wsb + 91619328);    // 214,958,080  (2048*OPAD*2)
    float* dtv   = (float*)(wsb + 319160320); //  12,582,912
    float* ybuf  = (float*)(wsb + 331743232); //  12,582,912
    float* resb  = (float*)(wsb + 344326144); //  12,582,912
    u16* gbuf    = (u16*)(wsb + 356909056);   //   6,291,456  -> total 363,200,512
    float* chkA  = (float*)(wsb + 0);         //  12,582,912 (64*2*1536*16*4)
    float* chkB  = (float*)(wsb + 12582912);  //  12,582,912
    float* hst   = (float*)(wsb + 25165824);  //  12,582,912 (ends 37.7MB)

    // 1) weight converts (W_res / W_out only; W_in consumed as f32 by gemm256)
    cvt_kernel<<<1152, 256, 0, stream>>>(W_res, Wresbf, (long)DI * DM, (long)DI * DM);
    cvt_kernel<<<1152, 256, 0, stream>>>(W_out, Woutbf, (long)DM * DI, (long)DM * DI);
    // 2) layernorm
    ln_kernel<<<2048, 256, 0, stream>>>(x, ln_w, ln_b, xnbf, xbf);
    // 3) big GEMM: p = xn @ W_in^T (bf16 out, ldc = OPAD); 256^2 8-phase
    gemm256_bt<<<dim3(8, 205), 512, 0, stream>>>(xnbf, W_in, pbuf, DM, OPAD);
    // 4) res = x @ W_res^T (f32 out)
    gemm_bt<0><<<dim3(16, 12), 256, 0, stream>>>(xbf, Wresbf, resb, DM, DI);
    // 5) dt
    dt_kernel<<<128, 256, 0, stream>>>(pbuf, W_dt, dt_bias, dtv);
    // 6) scan v3: chunk-parallel, lane-owns-d, conv fused
    scan1_kernel<<<dim3(6, 2, SCAN_P), 256, 0, stream>>>(pbuf, dtv, A_log, conv_w, conv_b, chkA, chkB);
    scan_comb_kernel<<<192, 256, 0, stream>>>(chkA, chkB, hst);
    scan2_kernel<<<dim3(6, 2, SCAN_P), 256, 0, stream>>>(pbuf, dtv, A_log, conv_w, conv_b, Dskip, hst, ybuf);
    // 7) gate + rmsnorm + residual
    gate_kernel<<<2048, 256, 0, stream>>>(pbuf, ybuf, resb, norm_w, gbuf);
    // 8) out = g @ W_out^T (f32 out)
    gemm_bt<0><<<dim3(16, 6), 256, 0, stream>>>(gbuf, Woutbf, out, DI, DM);
}

// Round 5
// 691.411 us; speedup vs baseline: 1.2927x; 1.2927x over previous
//
#include <hip/hip_runtime.h>

// HybridMambaBlock pipeline:
//  1) cvt: W_in/W_res/W_out f32 -> bf16 (W_in padded to OPAD rows, zero fill)
//  2) ln: LayerNorm(x) -> xn(bf16); also x -> bf16 for the residual GEMM
//  3) gemm256_bt: p = xn @ W_in^T (2048 x 52480) -- 256^2 8-phase schedule
//  4) gemm_bt<f32 out>:  res = x @ W_res^T
//  5) dt: dt = clip(softplus(dth @ W_dt^T + bias), 1e-4, 1)
//  6) scan v3: chunk-parallel (P=64), lane-owns-d; depthwise conv K=4 fused
//     inline (conv_kernel + ucv round-trip eliminated; bit-identical math)
//  7) gate: g = rmsnorm(y*silu(z))*norm_w + res -> bf16
//  8) gemm_bt<f32 out>: out = g @ W_out^T
//
// R10: revert gemm256 to the R8 form (bf16 B staged from pre-converted Wbf;
//   213us, 0 bank conflicts). R9's in-kernel f32->bf16 B staging serialized
//   the pipeline (vmcnt wait EVERY phase + 2-phase B lookahead < HBM latency
//   -> gemm256 474us, MfmaUtil 14%). Scratch depth can't grow past 160KB LDS,
//   so that design is abandoned, not patched.
//   KEPT from R9 (proven, -72us non-gemm): conv fused into scan1/scan2,
//   P=64 scan chunking, parallel scan_comb.

typedef unsigned short u16;
typedef __bf16 bf16x8 __attribute__((ext_vector_type(8)));
typedef float f32x4 __attribute__((ext_vector_type(4)));

#define OPAD 52480   // 205*256 >= 52272 ; row stride of p, padded rows of Wbf
#define OTOT 52272
#define DI   1536
#define DM   768
#define Z0   0
#define U0   1536
#define DTH0 3072
#define B0   3120
#define C0   27696

#define SCAN_P 64
#define SCAN_T 16    // 1024 / SCAN_P
#define SPF    4     // prefetch ring depth (must divide SCAN_T)

__device__ static inline u16 f2bf(float f) {
    unsigned u = __float_as_uint(f);
    u += 0x7fffu + ((u >> 16) & 1u);
    return (u16)(u >> 16);
}
__device__ static inline float bf2f(u16 s) {
    return __uint_as_float(((unsigned)s) << 16);
}

__device__ static inline void gload16(const void* g, void* l) {
    __builtin_amdgcn_global_load_lds(
        (const __attribute__((address_space(1))) unsigned int*)g,
        (__attribute__((address_space(3))) unsigned int*)l, 16, 0, 0);
}

// unpack 8 bf16 (as uint4) -> 8 f32, memory order preserved
__device__ static inline void unpack8(uint4 v, float* f) {
    unsigned w0 = v.x, w1 = v.y, w2 = v.z, w3 = v.w;
    f[0] = __uint_as_float(w0 << 16); f[1] = __uint_as_float(w0 & 0xffff0000u);
    f[2] = __uint_as_float(w1 << 16); f[3] = __uint_as_float(w1 & 0xffff0000u);
    f[4] = __uint_as_float(w2 << 16); f[5] = __uint_as_float(w2 & 0xffff0000u);
    f[6] = __uint_as_float(w3 << 16); f[7] = __uint_as_float(w3 & 0xffff0000u);
}

// ---------------- f32 -> bf16 convert (with zero pad to n_tot) ----------------
__global__ void cvt_kernel(const float* __restrict__ src, u16* __restrict__ dst,
                           long n_src, long n_tot) {
    long i4 = ((long)blockIdx.x * 256 + threadIdx.x) * 4;
    if (i4 >= n_tot) return;
    ushort4 o;
    if (i4 < n_src) {  // n_src is a multiple of 4 for all callers
        float4 v = *(const float4*)(src + i4);
        o.x = f2bf(v.x); o.y = f2bf(v.y); o.z = f2bf(v.z); o.w = f2bf(v.w);
    } else {
        o.x = o.y = o.z = o.w = 0;
    }
    *(ushort4*)(dst + i4) = o;
}

// ---------------- block reduce (sum of two values across 256 threads) --------
__device__ static inline void block_reduce2(float& a, float& b) {
    #pragma unroll
    for (int o = 32; o > 0; o >>= 1) {
        a += __shfl_down(a, o);
        b += __shfl_down(b, o);
    }
    __shared__ float sa[4], sb[4];
    int lane = threadIdx.x & 63, w = threadIdx.x >> 6;
    if (lane == 0) { sa[w] = a; sb[w] = b; }
    __syncthreads();
    a = sa[0] + sa[1] + sa[2] + sa[3];
    b = sb[0] + sb[1] + sb[2] + sb[3];
}

// ---------------- LayerNorm -> xn bf16, plus raw x -> bf16 -------------------
__global__ void __launch_bounds__(256) ln_kernel(const float* __restrict__ x,
        const float* __restrict__ w, const float* __restrict__ b,
        u16* __restrict__ xnbf, u16* __restrict__ xbf) {
    int m = blockIdx.x, tid = threadIdx.x;
    const float* xr = x + (size_t)m * DM;
    float v[3];
    v[0] = xr[tid]; v[1] = xr[tid + 256]; v[2] = xr[tid + 512];
    float s = v[0] + v[1] + v[2];
    float ss = v[0]*v[0] + v[1]*v[1] + v[2]*v[2];
    block_reduce2(s, ss);
    float mu = s * (1.f / DM);
    float var = ss * (1.f / DM) - mu * mu;
    float inv = rsqrtf(var + 1e-5f);
    #pragma unroll
    for (int i = 0; i < 3; ++i) {
        int d = tid + i * 256;
        float xn = (v[i] - mu) * inv * w[d] + b[d];
        xnbf[(size_t)m * DM + d] = f2bf(xn);
        xbf[(size_t)m * DM + d] = f2bf(v[i]);
    }
}

// ---------------- bf16 MFMA GEMM: C[M,N] = A[M,K] * B[N,K]^T -----------------
// 128x128 tile, BK=64, 256 threads. Used for the two small GEMMs (res, out).
template <int OUT_BF16>
__global__ void __launch_bounds__(256) gemm_bt(const u16* __restrict__ A,
        const u16* __restrict__ B, void* __restrict__ C, int K, int ldc) {
    __shared__ u16 smem[2 * 128 * 64];
    u16* As = smem;
    u16* Bs = smem + 128 * 64;
    int tid = threadIdx.x;
    int m0 = blockIdx.x * 128, n0 = blockIdx.y * 128;
    int lane = tid & 63, wave = tid >> 6;
    int wm = wave >> 1, wn = wave & 1;
    int l15 = lane & 15, l4 = lane >> 4;
    f32x4 acc[4][4] = {};
    const u16* Ag = A + (size_t)m0 * K;
    const u16* Bg = B + (size_t)n0 * K;
    int crow = tid >> 3;
    int ccol = ((tid & 7) ^ ((tid >> 3) & 7)) * 8;
    int ldsoff = (tid & 192) * 16;
    int xr = l15 & 7;

    for (int k0 = 0; k0 < K; k0 += 64) {
        __syncthreads();
        #pragma unroll
        for (int it = 0; it < 4; ++it) {
            gload16(Ag + (size_t)(it * 32 + crow) * K + k0 + ccol,
                    (char*)As + it * 4096 + ldsoff);
            gload16(Bg + (size_t)(it * 32 + crow) * K + k0 + ccol,
                    (char*)Bs + it * 4096 + ldsoff);
        }
        __syncthreads();
        const u16* Arow = As + (wm * 64 + l15) * 64;
        const u16* Brow = Bs + (wn * 64 + l15) * 64;
        #pragma unroll
        for (int kk8 = 0; kk8 < 8; kk8 += 4) {
            int sw = ((l4 + kk8) ^ xr) * 8;
            bf16x8 af[4], bfr[4];
            #pragma unroll
            for (int i = 0; i < 4; ++i) af[i] = *(const bf16x8*)(Arow + i * 16 * 64 + sw);
            #pragma unroll
            for (int j = 0; j < 4; ++j) bfr[j] = *(const bf16x8*)(Brow + j * 16 * 64 + sw);
            #pragma unroll
            for (int i = 0; i < 4; ++i)
                #pragma unroll
                for (int j = 0; j < 4; ++j)
                    acc[i][j] = __builtin_amdgcn_mfma_f32_16x16x32_bf16(
                        af[i], bfr[j], acc[i][j], 0, 0, 0);
        }
    }
    #pragma unroll
    for (int i = 0; i < 4; ++i) {
        int row = m0 + wm * 64 + i * 16 + l4 * 4;
        #pragma unroll
        for (int j = 0; j < 4; ++j) {
            int col = n0 + wn * 64 + j * 16 + l15;
            #pragma unroll
            for (int r = 0; r < 4; ++r) {
                size_t off = (size_t)(row + r) * ldc + col;
                if (OUT_BF16) ((u16*)C)[off] = f2bf(acc[i][j][r]);
                else          ((float*)C)[off] = acc[i][j][r];
            }
        }
    }
}

// ---------------- 256x256 8-phase bf16 GEMM (the big GEMM) -------------------
// C[M,N](bf16) = A[M,K] * B[N,K]^T. 512 threads (8 waves, 2Mx4N), BK=64.
// LDS 128 KiB: 2 buffers x {A 2x(256x32), B 2x(256x32)} K-split half-slots.
// Half-slot internal layout (R8): [128 LDS-rows][128 B]; LDS-row R packs
// m-rows {2R, 2R+1} at 16B slot granularity, slot = (2*kseg+(m&1)) ^ 2*(R&3).
// Staging linear per gload chunk (permute folded into per-lane global src);
// each wave frag-read covers 8 full 128-B rows -> conflict-free (measured 0).
// Per phase: stage one half-slot (2 global_load_lds) || ds_reads ->
// s_barrier -> setprio(1) 16 MFMA setprio(0) -> [vmcnt(4) at phases 2,4] ->
// s_barrier. vmcnt never drains to 0 in the main loop.
#define G2_BUF  65536
#define G2_HALF 16384
#define G2_BOFF 32768

__global__ void __launch_bounds__(512, 2) gemm256_bt(const u16* __restrict__ A,
        const u16* __restrict__ B, u16* __restrict__ C, int K, int ldc) {
    __shared__ u16 smem[65536];           // 128 KiB
    char* smemc = (char*)smem;
    const int tid = threadIdx.x;
    const int l = tid & 63, w = tid >> 6;          // lane, wave 0..7
    const int wm = w >> 2, wn = w & 3;             // 2 x 4 wave grid
    const int l15 = l & 15, l4 = l >> 4;
    // XCD-aware bijective remap (grid is exactly 8 x 205 = 1640 blocks).
    const int flat = blockIdx.y * 8 + blockIdx.x;
    const int wg = (flat & 7) * 205 + (flat >> 3);
    const int m0 = (wg & 7) * 256, n0 = (wg >> 3) * 256;
    const int NT = K >> 6;                         // K-tiles of 64 (even)

    // read side: lane offset within a half-slot.
    const int rA = l15 >> 1;
    const int rdoff = rA * 128 + ((((l4 << 1) + (l15 & 1)) ^ ((rA & 3) << 1)) << 4);
    // stage side: per-lane inverse-permuted global source
    const int wpr = (l & 7) ^ (((l >> 3) & 3) << 1);
    const int srow = w * 32 + ((l >> 3) << 1) + (wpr & 1);
    const u16* Ast = A + (size_t)(m0 + srow) * K + (wpr >> 1) * 8;
    const u16* Bst = B + (size_t)(n0 + srow) * K + (wpr >> 1) * 8;
    const int sdst = w * 2048;                     // wave-uniform LDS dest

    f32x4 acc[8][4] = {};
    bf16x8 bvK[4];                                 // live across rh0/rh1 pair

#define G2_STAGE(MATP, MOFF, nxt, sh, tk)                                      \
    gload16(MATP + (size_t)(tk) * 64 + (sh) * 32,                              \
            smemc + (nxt) * G2_BUF + (MOFF) + (sh) * G2_HALF + sdst);          \
    gload16(MATP + (size_t)16 * K + (size_t)(tk) * 64 + (sh) * 32,             \
            smemc + (nxt) * G2_BUF + (MOFF) + (sh) * G2_HALF + sdst + 1024);

#define G2_PHASE(cur, nxt, rh, h, READB, SMAT, SMOFF, sh, tk, DO_VM)           \
    {                                                                          \
        G2_STAGE(SMAT, SMOFF, nxt, sh, tk);                                    \
        const char* Ab = smemc + (cur) * G2_BUF + (h) * G2_HALF                \
                         + (wm * 128 + (rh) * 64) * 64 + rdoff;                \
        bf16x8 af[4];                                                          \
        if (READB) {                                                           \
            const char* Bb = smemc + (cur) * G2_BUF + G2_BOFF + (h) * G2_HALF  \
                             + (wn * 64) * 64 + rdoff;                         \
            _Pragma("unroll")                                                  \
            for (int j = 0; j < 4; ++j)                                        \
                bvK[j] = *(const bf16x8*)(Bb + j * 1024);                      \
        }                                                                      \
        _Pragma("unroll")                                                      \
        for (int i = 0; i < 4; ++i) af[i] = *(const bf16x8*)(Ab + i * 1024);   \
        __builtin_amdgcn_s_barrier();                                          \
        __builtin_amdgcn_s_setprio(1);                                         \
        _Pragma("unroll")                                                      \
        for (int i = 0; i < 4; ++i)                                            \
            _Pragma("unroll")                                                  \
            for (int j = 0; j < 4; ++j)                                        \
                acc[(rh) * 4 + i][j] = __builtin_amdgcn_mfma_f32_16x16x32_bf16(\
                    af[i], bvK[j], acc[(rh) * 4 + i][j], 0, 0, 0);             \
        __builtin_amdgcn_s_setprio(0);                                         \
        if (DO_VM) asm volatile("s_waitcnt vmcnt(4)" ::: "memory");            \
        __builtin_amdgcn_s_barrier();                                          \
    }

// tile t from buffer cur; stage tile tk into buffer nxt (one half-slot/phase,
// order A-K0, B-K0, A-K1, B-K1 -- same order the next tile consumes them)
#define G2_TILE(cur, nxt, tk)                                                  \
    G2_PHASE(cur, nxt, 0, 0, 1, Ast, 0,       0, tk, 0)                        \
    G2_PHASE(cur, nxt, 1, 0, 0, Bst, G2_BOFF, 0, tk, 1)                        \
    G2_PHASE(cur, nxt, 0, 1, 1, Ast, 0,       1, tk, 0)                        \
    G2_PHASE(cur, nxt, 1, 1, 0, Bst, G2_BOFF, 1, tk, 1)

    // prologue: stage tile 0 into buffer 0; wait K0 half-slots only
    G2_STAGE(Ast, 0,       0, 0, 0);
    G2_STAGE(Bst, G2_BOFF, 0, 0, 0);
    G2_STAGE(Ast, 0,       0, 1, 0);
    G2_STAGE(Bst, G2_BOFF, 0, 1, 0);
    asm volatile("s_waitcnt vmcnt(4)" ::: "memory");
    __builtin_amdgcn_s_barrier();

    for (int t = 0; t < NT; t += 2) {
        int tk1 = t + 1;                           // always <= NT-1 (NT even)
        int tk2 = (t + 2 < NT) ? t + 2 : NT - 1;   // clamp: harmless restage
        G2_TILE(0, 1, tk1)
        G2_TILE(1, 0, tk2)
    }

    #pragma unroll
    for (int ai = 0; ai < 8; ++ai) {
        int row = m0 + wm * 128 + ai * 16 + l4 * 4;
        #pragma unroll
        for (int j = 0; j < 4; ++j) {
            int col = n0 + wn * 64 + j * 16 + l15;
            #pragma unroll
            for (int r = 0; r < 4; ++r)
                C[(size_t)(row + r) * ldc + col] = f2bf(acc[ai][j][r]);
        }
    }
#undef G2_STAGE
#undef G2_PHASE
#undef G2_TILE
}

// ---------------- dt = clip(softplus(dth @ W_dt^T + bias)) -------------------
__global__ void __launch_bounds__(256) dt_kernel(const u16* __restrict__ p,
        const float* __restrict__ Wdt, const float* __restrict__ dt_bias,
        float* __restrict__ dt) {
    int m0 = blockIdx.x * 16, tid = threadIdx.x;
    __shared__ float dth_s[16 * 48];
    for (int i = tid; i < 16 * 48; i += 256)
        dth_s[i] = bf2f(p[(size_t)(m0 + i / 48) * OPAD + DTH0 + (i % 48)]);
    __syncthreads();
    #pragma unroll
    for (int ii = 0; ii < 6; ++ii) {
        int d = ii * 256 + tid;
        float base = dt_bias[d];
        float acc[16];
        #pragma unroll
        for (int mm = 0; mm < 16; ++mm) acc[mm] = base;
        for (int r = 0; r < 48; ++r) {
            float wv = Wdt[d * 48 + r];
            #pragma unroll
            for (int mm = 0; mm < 16; ++mm)
                acc[mm] = fmaf(wv, dth_s[mm * 48 + r], acc[mm]);
        }
        #pragma unroll
        for (int mm = 0; mm < 16; ++mm) {
            float xv = acc[mm];
            float sp = xv > 20.f ? xv : log1pf(__expf(xv));
            sp = fminf(fmaxf(sp, 1e-4f), 1.0f);
            dt[(size_t)(m0 + mm) * DI + d] = sp;
        }
    }
}

// ---------------- scan v3 pass 1: per-chunk (A,h) summaries, conv fused ------
__global__ void __launch_bounds__(256, 2) scan1_kernel(const u16* __restrict__ p,
        const float* __restrict__ dt, const float* __restrict__ A_log,
        const float* __restrict__ cw, const float* __restrict__ cb,
        float* __restrict__ chkA, float* __restrict__ chkB) {
    int d = blockIdx.x * 256 + threadIdx.x;
    int b = blockIdx.y, c = blockIdx.z;
    int t0base = c * SCAN_T;
    float a[16];
    #pragma unroll
    for (int n = 0; n < 16; ++n) a[n] = -__expf(A_log[d * 16 + n]);
    float cw0 = cw[d*4], cw1 = cw[d*4+1], cw2 = cw[d*4+2], cw3 = cw[d*4+3];
    float cbv = cb[d];
    const u16* pB = p + (size_t)(b * 1024 + t0base) * OPAD + B0 + d * 16;
    const u16* pU = p + (size_t)(b * 1024 + t0base) * OPAD + U0 + d;
    const float* dtp = dt + (size_t)(b * 1024 + t0base) * DI + d;
    float x1, x2, x3;  // u-raw history x[t-1], x[t-2], x[t-3]
    if (c == 0) { x1 = x2 = x3 = 0.f; }
    else {
        x1 = bf2f(*(pU - (long)OPAD));
        x2 = bf2f(*(pU - 2L * OPAD));
        x3 = bf2f(*(pU - 3L * OPAD));
    }
    uint4 Br[SPF][2]; float dtr[SPF], xur[SPF];
    #pragma unroll
    for (int i = 0; i < SPF; ++i) {
        Br[i][0] = *(const uint4*)(pB + (size_t)i * OPAD);
        Br[i][1] = *(const uint4*)(pB + (size_t)i * OPAD + 8);
        dtr[i] = dtp[(size_t)i * DI];
        xur[i] = bf2f(pU[(size_t)i * OPAD]);
    }
    float h[16], Av[16];
    #pragma unroll
    for (int n = 0; n < 16; ++n) { h[n] = 0.f; Av[n] = 1.f; }
    for (int t0 = 0; t0 < SCAN_T; t0 += SPF) {
        #pragma unroll
        for (int s = 0; s < SPF; ++s) {
            int t = t0 + s;
            uint4 b0 = Br[s][0], b1 = Br[s][1];
            float dtv = dtr[s], xt = xur[s];
            int tl = t + SPF < SCAN_T ? t + SPF : SCAN_T - 1;
            Br[s][0] = *(const uint4*)(pB + (size_t)tl * OPAD);
            Br[s][1] = *(const uint4*)(pB + (size_t)tl * OPAD + 8);
            dtr[s] = dtp[(size_t)tl * DI];
            xur[s] = bf2f(pU[(size_t)tl * OPAD]);
            float uv = cbv;
            uv = fmaf(cw0, x3, uv);
            uv = fmaf(cw1, x2, uv);
            uv = fmaf(cw2, x1, uv);
            uv = fmaf(cw3, xt, uv);
            x3 = x2; x2 = x1; x1 = xt;
            float Bf[16];
            unpack8(b0, Bf); unpack8(b1, Bf + 8);
            float dtu = dtv * uv;
            #pragma unroll
            for (int n = 0; n < 16; ++n) {
                float dA = __expf(dtv * a[n]);
                h[n] = fmaf(dA, h[n], dtu * Bf[n]);
                Av[n] *= dA;
            }
        }
    }
    size_t o = (((size_t)c * 2 + b) * 1536 + d) * 16;
    #pragma unroll
    for (int k = 0; k < 4; ++k) {
        *(float4*)(chkA + o + k * 4) = make_float4(Av[4*k], Av[4*k+1], Av[4*k+2], Av[4*k+3]);
        *(float4*)(chkB + o + k * 4) = make_float4(h[4*k], h[4*k+1], h[4*k+2], h[4*k+3]);
    }
}

// ---------------- scan v3 pass 2: fold chunk summaries -> h_start ------------
// One thread per (b,d,n): 49152 threads / 192 blocks.
__global__ void __launch_bounds__(256) scan_comb_kernel(const float* __restrict__ chkA,
        const float* __restrict__ chkB, float* __restrict__ hstart) {
    int idx = blockIdx.x * 256 + threadIdx.x;  // b*24576 + d*16 + n
    float hs = 0.f;
    for (int c = 0; c < SCAN_P; ++c) {
        size_t o = (size_t)c * 49152 + idx;
        hstart[o] = hs;
        hs = fmaf(chkA[o], hs, chkB[o]);
    }
}

// ---------------- scan v3 pass 3: replay with h_start, emit y; conv fused ----
__global__ void __launch_bounds__(256, 2) scan2_kernel(const u16* __restrict__ p,
        const float* __restrict__ dt, const float* __restrict__ A_log,
        const float* __restrict__ cw, const float* __restrict__ cb,
        const float* __restrict__ Dskip,
        const float* __restrict__ hstart, float* __restrict__ y) {
    int d = blockIdx.x * 256 + threadIdx.x;
    int b = blockIdx.y, c = blockIdx.z;
    int t0base = c * SCAN_T;
    float a[16];
    #pragma unroll
    for (int n = 0; n < 16; ++n) a[n] = -__expf(A_log[d * 16 + n]);
    float Dsk = Dskip[d];
    float cw0 = cw[d*4], cw1 = cw[d*4+1], cw2 = cw[d*4+2], cw3 = cw[d*4+3];
    float cbv = cb[d];
    const u16* pB = p + (size_t)(b * 1024 + t0base) * OPAD + B0 + d * 16;
    const u16* pC = p + (size_t)(b * 1024 + t0base) * OPAD + C0 + d * 16;
    const u16* pU = p + (size_t)(b * 1024 + t0base) * OPAD + U0 + d;
    const float* dtp = dt + (size_t)(b * 1024 + t0base) * DI + d;
    float* yp        = y  + (size_t)(b * 1024 + t0base) * DI + d;
    float x1, x2, x3;
    if (c == 0) { x1 = x2 = x3 = 0.f; }
    else {
        x1 = bf2f(*(pU - (long)OPAD));
        x2 = bf2f(*(pU - 2L * OPAD));
        x3 = bf2f(*(pU - 3L * OPAD));
    }
    uint4 Br[SPF][2], Cr[SPF][2]; float dtr[SPF], xur[SPF];
    #pragma unroll
    for (int i = 0; i < SPF; ++i) {
        Br[i][0] = *(const uint4*)(pB + (size_t)i * OPAD);
        Br[i][1] = *(const uint4*)(pB + (size_t)i * OPAD + 8);
        Cr[i][0] = *(const uint4*)(pC + (size_t)i * OPAD);
        Cr[i][1] = *(const uint4*)(pC + (size_t)i * OPAD + 8);
        dtr[i] = dtp[(size_t)i * DI];
        xur[i] = bf2f(pU[(size_t)i * OPAD]);
    }
    float h[16];
    {
        size_t o = ((size_t)c * 3072 + (size_t)b * 1536 + d) * 16;
        #pragma unroll
        for (int k = 0; k < 4; ++k) {
            float4 hv = *(const float4*)(hstart + o + k * 4);
            h[4*k] = hv.x; h[4*k+1] = hv.y; h[4*k+2] = hv.z; h[4*k+3] = hv.w;
        }
    }
    for (int t0 = 0; t0 < SCAN_T; t0 += SPF) {
        #pragma unroll
        for (int s = 0; s < SPF; ++s) {
            int t = t0 + s;
            uint4 b0 = Br[s][0], b1 = Br[s][1], c0 = Cr[s][0], c1 = Cr[s][1];
            float dtv = dtr[s], xt = xur[s];
            int tl = t + SPF < SCAN_T ? t + SPF : SCAN_T - 1;
            Br[s][0] = *(const uint4*)(pB + (size_t)tl * OPAD);
            Br[s][1] = *(const uint4*)(pB + (size_t)tl * OPAD + 8);
            Cr[s][0] = *(const uint4*)(pC + (size_t)tl * OPAD);
            Cr[s][1] = *(const uint4*)(pC + (size_t)tl * OPAD + 8);
            dtr[s] = dtp[(size_t)tl * DI];
            xur[s] = bf2f(pU[(size_t)tl * OPAD]);
            float uv = cbv;
            uv = fmaf(cw0, x3, uv);
            uv = fmaf(cw1, x2, uv);
            uv = fmaf(cw2, x1, uv);
            uv = fmaf(cw3, xt, uv);
            x3 = x2; x2 = x1; x1 = xt;
            float Bf[16], Cf[16];
            unpack8(b0, Bf); unpack8(b1, Bf + 8);
            unpack8(c0, Cf); unpack8(c1, Cf + 8);
            float dtu = dtv * uv;
            #pragma unroll
            for (int n = 0; n < 16; ++n) {
                float dA = __expf(dtv * a[n]);
                h[n] = fmaf(dA, h[n], dtu * Bf[n]);
            }
            float a0 = fmaf(Cf[0], h[0], uv * Dsk), a1 = Cf[1] * h[1];
            float a2 = Cf[2] * h[2], a3 = Cf[3] * h[3];
            #pragma unroll
            for (int n = 4; n < 16; n += 4) {
                a0 = fmaf(Cf[n],   h[n],   a0);
                a1 = fmaf(Cf[n+1], h[n+1], a1);
                a2 = fmaf(Cf[n+2], h[n+2], a2);
                a3 = fmaf(Cf[n+3], h[n+3], a3);
            }
            yp[(size_t)t * DI] = (a0 + a1) + (a2 + a3);
        }
    }
}

// ---------------- gating + RMSNorm + residual -> g (bf16) --------------------
__global__ void __launch_bounds__(256) gate_kernel(const u16* __restrict__ p,
        const float* __restrict__ y, const float* __restrict__ res,
        const float* __restrict__ norm_w, u16* __restrict__ g) {
    int m = blockIdx.x, tid = threadIdx.x;
    const u16* pz = p + (size_t)m * OPAD + Z0;
    const float* yr = y + (size_t)m * DI;
    float gp[6];
    float ss = 0.f, dummy = 0.f;
    #pragma unroll
    for (int i = 0; i < 6; ++i) {
        int d = i * 256 + tid;
        float z = bf2f(pz[d]);
        float gv = yr[d] * z / (1.f + __expf(-z));
        gp[i] = gv;
        ss += gv * gv;
    }
    block_reduce2(ss, dummy);
    float scale = rsqrtf(ss * (1.f / DI) + 1e-6f);
    #pragma unroll
    for (int i = 0; i < 6; ++i) {
        int d = i * 256 + tid;
        float val = gp[i] * scale * norm_w[d] + res[(size_t)m * DI + d];
        g[(size_t)m * DI + d] = f2bf(val);
    }
}

// ---------------- host ----------------
extern "C" void kernel_launch(void* const* d_in, const int* in_sizes, int n_in,
                              void* d_out, int out_size, void* d_ws, size_t ws_size,
                              hipStream_t stream) {
    const float* x       = (const float*)d_in[0];
    const float* ln_w    = (const float*)d_in[1];
    const float* ln_b    = (const float*)d_in[2];
    const float* W_in    = (const float*)d_in[3];
    const float* W_dt    = (const float*)d_in[4];
    const float* conv_w  = (const float*)d_in[5];
    const float* conv_b  = (const float*)d_in[6];
    const float* A_log   = (const float*)d_in[7];
    const float* Dskip   = (const float*)d_in[8];
    const float* dt_bias = (const float*)d_in[9];
    const float* norm_w  = (const float*)d_in[10];
    const float* W_res   = (const float*)d_in[11];
    const float* W_out   = (const float*)d_in[12];
    float* out = (float*)d_out;

    char* wsb = (char*)d_ws;
    u16* Wbf     = (u16*)(wsb + 0);           //  80,609,280  (OPAD*768*2)
    u16* Wresbf  = (u16*)(wsb + 80609280);    //   2,359,296
    u16* Woutbf  = (u16*)(wsb + 82968576);    //   2,359,296
    u16* xnbf    = (u16*)(wsb + 85327872);    //   3,145,728
    u16* xbf     = (u16*)(wsb + 88473600);    //   3,145,728
    u16* pbuf    = (u16*)(wsb + 91619328);    // 214,958,080  (2048*OPAD*2)
    float* dtv   = (float*)(wsb + 319160320); //  12,582,912
    float* ybuf  = (float*)(wsb + 331743232); //  12,582,912
    float* resb  = (float*)(wsb + 344326144); //  12,582,912
    u16* gbuf    = (u16*)(wsb + 356909056);   //   6,291,456  -> total 363,200,512
    // scan chunk buffers alias the Wbf region (dead after gemm1):
    float* chkA  = (float*)(wsb + 0);         //  12,582,912 (64*2*1536*16*4)
    float* chkB  = (float*)(wsb + 12582912);  //  12,582,912
    float* hst   = (float*)(wsb + 25165824);  //  12,582,912 (ends 37.7MB < 80.6MB)

    // 1) weight converts
    cvt_kernel<<<39360, 256, 0, stream>>>(W_in, Wbf, (long)OTOT * DM, (long)OPAD * DM);
    cvt_kernel<<<1152, 256, 0, stream>>>(W_res, Wresbf, (long)DI * DM, (long)DI * DM);
    cvt_kernel<<<1152, 256, 0, stream>>>(W_out, Woutbf, (long)DM * DI, (long)DM * DI);
    // 2) layernorm
    ln_kernel<<<2048, 256, 0, stream>>>(x, ln_w, ln_b, xnbf, xbf);
    // 3) big GEMM: p = xn @ W_in^T (bf16 out, ldc = OPAD); 256^2 8-phase
    gemm256_bt<<<dim3(8, 205), 512, 0, stream>>>(xnbf, Wbf, pbuf, DM, OPAD);
    // 4) res = x @ W_res^T (f32 out)
    gemm_bt<0><<<dim3(16, 12), 256, 0, stream>>>(xbf, Wresbf, resb, DM, DI);
    // 5) dt
    dt_kernel<<<128, 256, 0, stream>>>(pbuf, W_dt, dt_bias, dtv);
    // 6) scan v3: chunk-parallel, lane-owns-d, conv fused
    scan1_kernel<<<dim3(6, 2, SCAN_P), 256, 0, stream>>>(pbuf, dtv, A_log, conv_w, conv_b, chkA, chkB);
    scan_comb_kernel<<<192, 256, 0, stream>>>(chkA, chkB, hst);
    scan2_kernel<<<dim3(6, 2, SCAN_P), 256, 0, stream>>>(pbuf, dtv, A_log, conv_w, conv_b, Dskip, hst, ybuf);
    // 7) gate + rmsnorm + residual
    gate_kernel<<<2048, 256, 0, stream>>>(pbuf, ybuf, resb, norm_w, gbuf);
    // 8) out = g @ W_out^T (f32 out)
    gemm_bt<0><<<dim3(16, 6), 256, 0, stream>>>(gbuf, Woutbf, out, DI, DM);
}

// Round 6
// 664.933 us; speedup vs baseline: 1.3442x; 1.0398x over previous
//
#include <hip/hip_runtime.h>

// HybridMambaBlock pipeline:
//  1) cvt: W_in/W_res/W_out f32 -> bf16 (W_in padded to OPAD rows, zero fill)
//  2) ln: LayerNorm(x) -> xn(bf16); also x -> bf16 for the residual GEMM
//  3) gemm256_bt: p = xn @ W_in^T (2048 x 52480) -- 256^2 2-phase/tile schedule
//  4) gemm_bt<f32 out>:  res = x @ W_res^T
//  5) dt: dt = clip(softplus(dth @ W_dt^T + bias), 1e-4, 1)
//  6) scan v3: chunk-parallel (P=64), lane-owns-d; depthwise conv K=4 fused
//  7) gate: g = rmsnorm(y*silu(z))*norm_w + res -> bf16
//  8) gemm_bt<f32 out>: out = g @ W_out^T
//
// R11:
//  - gemm256: merged the 4 phases/K-tile into 2 (one per K=32 half).
//    R10 calibration: phase wall 1640cy vs 620cy MFMA content/SIMD -> the
//    ~1000cy/phase slack is barrier re-convergence (8 barriers/tile, 1
//    block/CU, nothing to cross-cover). Now 32 MFMA + 12 ds_read + 4 gload
//    per phase, 4 barriers/tile. vmcnt(4) at EVERY phase end: forces the
//    previous phase's 4 gloads complete (issued 1 phase ~1700cy earlier,
//    > HBM latency); consuming ds_reads are 1 further barrier away. WAR:
//    buffer-half overwritten >=2 phase-barriers after last read (same
//    margin as R8). Prologue unchanged. Per-acc MFMA order h0-then-h1
//    unchanged -> bit-identical C. Read layout/XCD remap/staging unchanged.
//  - dt_kernel: grid 128 -> 512 blocks (4 rows/block), same fmaf order.

typedef unsigned short u16;
typedef __bf16 bf16x8 __attribute__((ext_vector_type(8)));
typedef float f32x4 __attribute__((ext_vector_type(4)));

#define OPAD 52480   // 205*256 >= 52272 ; row stride of p, padded rows of Wbf
#define OTOT 52272
#define DI   1536
#define DM   768
#define Z0   0
#define U0   1536
#define DTH0 3072
#define B0   3120
#define C0   27696

#define SCAN_P 64
#define SCAN_T 16    // 1024 / SCAN_P
#define SPF    4     // prefetch ring depth (must divide SCAN_T)

__device__ static inline u16 f2bf(float f) {
    unsigned u = __float_as_uint(f);
    u += 0x7fffu + ((u >> 16) & 1u);
    return (u16)(u >> 16);
}
__device__ static inline float bf2f(u16 s) {
    return __uint_as_float(((unsigned)s) << 16);
}

__device__ static inline void gload16(const void* g, void* l) {
    __builtin_amdgcn_global_load_lds(
        (const __attribute__((address_space(1))) unsigned int*)g,
        (__attribute__((address_space(3))) unsigned int*)l, 16, 0, 0);
}

// unpack 8 bf16 (as uint4) -> 8 f32, memory order preserved
__device__ static inline void unpack8(uint4 v, float* f) {
    unsigned w0 = v.x, w1 = v.y, w2 = v.z, w3 = v.w;
    f[0] = __uint_as_float(w0 << 16); f[1] = __uint_as_float(w0 & 0xffff0000u);
    f[2] = __uint_as_float(w1 << 16); f[3] = __uint_as_float(w1 & 0xffff0000u);
    f[4] = __uint_as_float(w2 << 16); f[5] = __uint_as_float(w2 & 0xffff0000u);
    f[6] = __uint_as_float(w3 << 16); f[7] = __uint_as_float(w3 & 0xffff0000u);
}

// ---------------- f32 -> bf16 convert (with zero pad to n_tot) ----------------
__global__ void cvt_kernel(const float* __restrict__ src, u16* __restrict__ dst,
                           long n_src, long n_tot) {
    long i4 = ((long)blockIdx.x * 256 + threadIdx.x) * 4;
    if (i4 >= n_tot) return;
    ushort4 o;
    if (i4 < n_src) {  // n_src is a multiple of 4 for all callers
        float4 v = *(const float4*)(src + i4);
        o.x = f2bf(v.x); o.y = f2bf(v.y); o.z = f2bf(v.z); o.w = f2bf(v.w);
    } else {
        o.x = o.y = o.z = o.w = 0;
    }
    *(ushort4*)(dst + i4) = o;
}

// ---------------- block reduce (sum of two values across 256 threads) --------
__device__ static inline void block_reduce2(float& a, float& b) {
    #pragma unroll
    for (int o = 32; o > 0; o >>= 1) {
        a += __shfl_down(a, o);
        b += __shfl_down(b, o);
    }
    __shared__ float sa[4], sb[4];
    int lane = threadIdx.x & 63, w = threadIdx.x >> 6;
    if (lane == 0) { sa[w] = a; sb[w] = b; }
    __syncthreads();
    a = sa[0] + sa[1] + sa[2] + sa[3];
    b = sb[0] + sb[1] + sb[2] + sb[3];
}

// ---------------- LayerNorm -> xn bf16, plus raw x -> bf16 -------------------
__global__ void __launch_bounds__(256) ln_kernel(const float* __restrict__ x,
        const float* __restrict__ w, const float* __restrict__ b,
        u16* __restrict__ xnbf, u16* __restrict__ xbf) {
    int m = blockIdx.x, tid = threadIdx.x;
    const float* xr = x + (size_t)m * DM;
    float v[3];
    v[0] = xr[tid]; v[1] = xr[tid + 256]; v[2] = xr[tid + 512];
    float s = v[0] + v[1] + v[2];
    float ss = v[0]*v[0] + v[1]*v[1] + v[2]*v[2];
    block_reduce2(s, ss);
    float mu = s * (1.f / DM);
    float var = ss * (1.f / DM) - mu * mu;
    float inv = rsqrtf(var + 1e-5f);
    #pragma unroll
    for (int i = 0; i < 3; ++i) {
        int d = tid + i * 256;
        float xn = (v[i] - mu) * inv * w[d] + b[d];
        xnbf[(size_t)m * DM + d] = f2bf(xn);
        xbf[(size_t)m * DM + d] = f2bf(v[i]);
    }
}

// ---------------- bf16 MFMA GEMM: C[M,N] = A[M,K] * B[N,K]^T -----------------
// 128x128 tile, BK=64, 256 threads. Used for the two small GEMMs (res, out).
template <int OUT_BF16>
__global__ void __launch_bounds__(256) gemm_bt(const u16* __restrict__ A,
        const u16* __restrict__ B, void* __restrict__ C, int K, int ldc) {
    __shared__ u16 smem[2 * 128 * 64];
    u16* As = smem;
    u16* Bs = smem + 128 * 64;
    int tid = threadIdx.x;
    int m0 = blockIdx.x * 128, n0 = blockIdx.y * 128;
    int lane = tid & 63, wave = tid >> 6;
    int wm = wave >> 1, wn = wave & 1;
    int l15 = lane & 15, l4 = lane >> 4;
    f32x4 acc[4][4] = {};
    const u16* Ag = A + (size_t)m0 * K;
    const u16* Bg = B + (size_t)n0 * K;
    int crow = tid >> 3;
    int ccol = ((tid & 7) ^ ((tid >> 3) & 7)) * 8;
    int ldsoff = (tid & 192) * 16;
    int xr = l15 & 7;

    for (int k0 = 0; k0 < K; k0 += 64) {
        __syncthreads();
        #pragma unroll
        for (int it = 0; it < 4; ++it) {
            gload16(Ag + (size_t)(it * 32 + crow) * K + k0 + ccol,
                    (char*)As + it * 4096 + ldsoff);
            gload16(Bg + (size_t)(it * 32 + crow) * K + k0 + ccol,
                    (char*)Bs + it * 4096 + ldsoff);
        }
        __syncthreads();
        const u16* Arow = As + (wm * 64 + l15) * 64;
        const u16* Brow = Bs + (wn * 64 + l15) * 64;
        #pragma unroll
        for (int kk8 = 0; kk8 < 8; kk8 += 4) {
            int sw = ((l4 + kk8) ^ xr) * 8;
            bf16x8 af[4], bfr[4];
            #pragma unroll
            for (int i = 0; i < 4; ++i) af[i] = *(const bf16x8*)(Arow + i * 16 * 64 + sw);
            #pragma unroll
            for (int j = 0; j < 4; ++j) bfr[j] = *(const bf16x8*)(Brow + j * 16 * 64 + sw);
            #pragma unroll
            for (int i = 0; i < 4; ++i)
                #pragma unroll
                for (int j = 0; j < 4; ++j)
                    acc[i][j] = __builtin_amdgcn_mfma_f32_16x16x32_bf16(
                        af[i], bfr[j], acc[i][j], 0, 0, 0);
        }
    }
    #pragma unroll
    for (int i = 0; i < 4; ++i) {
        int row = m0 + wm * 64 + i * 16 + l4 * 4;
        #pragma unroll
        for (int j = 0; j < 4; ++j) {
            int col = n0 + wn * 64 + j * 16 + l15;
            #pragma unroll
            for (int r = 0; r < 4; ++r) {
                size_t off = (size_t)(row + r) * ldc + col;
                if (OUT_BF16) ((u16*)C)[off] = f2bf(acc[i][j][r]);
                else          ((float*)C)[off] = acc[i][j][r];
            }
        }
    }
}

// ---------------- 256x256 2-phase/tile bf16 GEMM (the big GEMM) --------------
// C[M,N](bf16) = A[M,K] * B[N,K]^T. 512 threads (8 waves, 2Mx4N), BK=64.
// LDS 128 KiB: 2 buffers x {A 2x(256x32), B 2x(256x32)} K-split half-slots.
// Half-slot layout (R8, conflict-free measured 0): [128 LDS-rows][128 B];
// LDS-row R packs m-rows {2R,2R+1} at 16B slots, slot=(2*kseg+(m&1))^2*(R&3).
// Per phase (one per K-half): stage A-half + B-half of next tile (4 gloads)
// || 12 ds_reads (8 A-frags both rh, 4 B-frags) -> s_barrier -> setprio(1)
// 32 MFMA setprio(0) -> vmcnt(4) -> s_barrier.  4 barriers/tile (was 8).
#define G2_BUF  65536
#define G2_HALF 16384
#define G2_BOFF 32768

__global__ void __launch_bounds__(512, 2) gemm256_bt(const u16* __restrict__ A,
        const u16* __restrict__ B, u16* __restrict__ C, int K, int ldc) {
    __shared__ u16 smem[65536];           // 128 KiB
    char* smemc = (char*)smem;
    const int tid = threadIdx.x;
    const int l = tid & 63, w = tid >> 6;          // lane, wave 0..7
    const int wm = w >> 2, wn = w & 3;             // 2 x 4 wave grid
    const int l15 = l & 15, l4 = l >> 4;
    // XCD-aware bijective remap (grid is exactly 8 x 205 = 1640 blocks).
    const int flat = blockIdx.y * 8 + blockIdx.x;
    const int wg = (flat & 7) * 205 + (flat >> 3);
    const int m0 = (wg & 7) * 256, n0 = (wg >> 3) * 256;
    const int NT = K >> 6;                         // K-tiles of 64 (even)

    // read side: lane offset within a half-slot (packed row-pair layout).
    const int rA = l15 >> 1;
    const int rdoff = rA * 128 + ((((l4 << 1) + (l15 & 1)) ^ ((rA & 3) << 1)) << 4);
    // stage side: per-lane inverse-permuted global source
    const int wpr = (l & 7) ^ (((l >> 3) & 3) << 1);
    const int srow = w * 32 + ((l >> 3) << 1) + (wpr & 1);
    const u16* Ast = A + (size_t)(m0 + srow) * K + (wpr >> 1) * 8;
    const u16* Bst = B + (size_t)(n0 + srow) * K + (wpr >> 1) * 8;
    const int sdst = w * 2048;                     // wave-uniform LDS dest

    f32x4 acc[8][4] = {};

#define G2_STAGE(MATP, MOFF, nxt, sh, tk)                                      \
    gload16(MATP + (size_t)(tk) * 64 + (sh) * 32,                              \
            smemc + (nxt) * G2_BUF + (MOFF) + (sh) * G2_HALF + sdst);          \
    gload16(MATP + (size_t)16 * K + (size_t)(tk) * 64 + (sh) * 32,             \
            smemc + (nxt) * G2_BUF + (MOFF) + (sh) * G2_HALF + sdst + 1024);

#define G2_PHASE(cur, nxt, h, tk)                                              \
    {                                                                          \
        G2_STAGE(Ast, 0,       nxt, h, tk);                                    \
        G2_STAGE(Bst, G2_BOFF, nxt, h, tk);                                    \
        const char* Ab = smemc + (cur) * G2_BUF + (h) * G2_HALF                \
                         + (wm * 128) * 64 + rdoff;                            \
        const char* Bb = smemc + (cur) * G2_BUF + G2_BOFF + (h) * G2_HALF      \
                         + (wn * 64) * 64 + rdoff;                             \
        bf16x8 af0[4], af1[4], bv[4];                                          \
        _Pragma("unroll")                                                      \
        for (int j = 0; j < 4; ++j) bv[j] = *(const bf16x8*)(Bb + j * 1024);   \
        _Pragma("unroll")                                                      \
        for (int i = 0; i < 4; ++i) {                                          \
            af0[i] = *(const bf16x8*)(Ab + i * 1024);                          \
            af1[i] = *(const bf16x8*)(Ab + 4096 + i * 1024);                   \
        }                                                                      \
        __builtin_amdgcn_s_barrier();                                          \
        __builtin_amdgcn_s_setprio(1);                                         \
        _Pragma("unroll")                                                      \
        for (int i = 0; i < 4; ++i)                                            \
            _Pragma("unroll")                                                  \
            for (int j = 0; j < 4; ++j)                                        \
                acc[i][j] = __builtin_amdgcn_mfma_f32_16x16x32_bf16(           \
                    af0[i], bv[j], acc[i][j], 0, 0, 0);                        \
        _Pragma("unroll")                                                      \
        for (int i = 0; i < 4; ++i)                                            \
            _Pragma("unroll")                                                  \
            for (int j = 0; j < 4; ++j)                                        \
                acc[4 + i][j] = __builtin_amdgcn_mfma_f32_16x16x32_bf16(       \
                    af1[i], bv[j], acc[4 + i][j], 0, 0, 0);                    \
        __builtin_amdgcn_s_setprio(0);                                         \
        asm volatile("s_waitcnt vmcnt(4)" ::: "memory");                       \
        __builtin_amdgcn_s_barrier();                                          \
    }

// tile t from buffer cur; stage tile tk into buffer nxt (A-half + B-half per
// phase, consumed in the same order one tile later)
#define G2_TILE(cur, nxt, tk)                                                  \
    G2_PHASE(cur, nxt, 0, tk)                                                  \
    G2_PHASE(cur, nxt, 1, tk)

    // prologue: stage tile 0 into buffer 0; wait K0 half-slots only
    G2_STAGE(Ast, 0,       0, 0, 0);
    G2_STAGE(Bst, G2_BOFF, 0, 0, 0);
    G2_STAGE(Ast, 0,       0, 1, 0);
    G2_STAGE(Bst, G2_BOFF, 0, 1, 0);
    asm volatile("s_waitcnt vmcnt(4)" ::: "memory");
    __builtin_amdgcn_s_barrier();

    for (int t = 0; t < NT; t += 2) {
        int tk1 = t + 1;                           // always <= NT-1 (NT even)
        int tk2 = (t + 2 < NT) ? t + 2 : NT - 1;   // clamp: harmless restage
        G2_TILE(0, 1, tk1)
        G2_TILE(1, 0, tk2)
    }

    #pragma unroll
    for (int ai = 0; ai < 8; ++ai) {
        int row = m0 + wm * 128 + ai * 16 + l4 * 4;
        #pragma unroll
        for (int j = 0; j < 4; ++j) {
            int col = n0 + wn * 64 + j * 16 + l15;
            #pragma unroll
            for (int r = 0; r < 4; ++r)
                C[(size_t)(row + r) * ldc + col] = f2bf(acc[ai][j][r]);
        }
    }
#undef G2_STAGE
#undef G2_PHASE
#undef G2_TILE
}

// ---------------- dt = clip(softplus(dth @ W_dt^T + bias)) -------------------
// 512 blocks x 4 rows (was 128 x 16): full-chip occupancy, same fmaf order.
__global__ void __launch_bounds__(256) dt_kernel(const u16* __restrict__ p,
        const float* __restrict__ Wdt, const float* __restrict__ dt_bias,
        float* __restrict__ dt) {
    int m0 = blockIdx.x * 4, tid = threadIdx.x;
    __shared__ float dth_s[4 * 48];
    for (int i = tid; i < 4 * 48; i += 256)
        dth_s[i] = bf2f(p[(size_t)(m0 + i / 48) * OPAD + DTH0 + (i % 48)]);
    __syncthreads();
    #pragma unroll
    for (int ii = 0; ii < 6; ++ii) {
        int d = ii * 256 + tid;
        float base = dt_bias[d];
        float acc[4];
        #pragma unroll
        for (int mm = 0; mm < 4; ++mm) acc[mm] = base;
        for (int r = 0; r < 48; ++r) {
            float wv = Wdt[d * 48 + r];
            #pragma unroll
            for (int mm = 0; mm < 4; ++mm)
                acc[mm] = fmaf(wv, dth_s[mm * 48 + r], acc[mm]);
        }
        #pragma unroll
        for (int mm = 0; mm < 4; ++mm) {
            float xv = acc[mm];
            float sp = xv > 20.f ? xv : log1pf(__expf(xv));
            sp = fminf(fmaxf(sp, 1e-4f), 1.0f);
            dt[(size_t)(m0 + mm) * DI + d] = sp;
        }
    }
}

// ---------------- scan v3 pass 1: per-chunk (A,h) summaries, conv fused ------
__global__ void __launch_bounds__(256, 2) scan1_kernel(const u16* __restrict__ p,
        const float* __restrict__ dt, const float* __restrict__ A_log,
        const float* __restrict__ cw, const float* __restrict__ cb,
        float* __restrict__ chkA, float* __restrict__ chkB) {
    int d = blockIdx.x * 256 + threadIdx.x;
    int b = blockIdx.y, c = blockIdx.z;
    int t0base = c * SCAN_T;
    float a[16];
    #pragma unroll
    for (int n = 0; n < 16; ++n) a[n] = -__expf(A_log[d * 16 + n]);
    float cw0 = cw[d*4], cw1 = cw[d*4+1], cw2 = cw[d*4+2], cw3 = cw[d*4+3];
    float cbv = cb[d];
    const u16* pB = p + (size_t)(b * 1024 + t0base) * OPAD + B0 + d * 16;
    const u16* pU = p + (size_t)(b * 1024 + t0base) * OPAD + U0 + d;
    const float* dtp = dt + (size_t)(b * 1024 + t0base) * DI + d;
    float x1, x2, x3;  // u-raw history x[t-1], x[t-2], x[t-3]
    if (c == 0) { x1 = x2 = x3 = 0.f; }
    else {
        x1 = bf2f(*(pU - (long)OPAD));
        x2 = bf2f(*(pU - 2L * OPAD));
        x3 = bf2f(*(pU - 3L * OPAD));
    }
    uint4 Br[SPF][2]; float dtr[SPF], xur[SPF];
    #pragma unroll
    for (int i = 0; i < SPF; ++i) {
        Br[i][0] = *(const uint4*)(pB + (size_t)i * OPAD);
        Br[i][1] = *(const uint4*)(pB + (size_t)i * OPAD + 8);
        dtr[i] = dtp[(size_t)i * DI];
        xur[i] = bf2f(pU[(size_t)i * OPAD]);
    }
    float h[16], Av[16];
    #pragma unroll
    for (int n = 0; n < 16; ++n) { h[n] = 0.f; Av[n] = 1.f; }
    for (int t0 = 0; t0 < SCAN_T; t0 += SPF) {
        #pragma unroll
        for (int s = 0; s < SPF; ++s) {
            int t = t0 + s;
            uint4 b0 = Br[s][0], b1 = Br[s][1];
            float dtv = dtr[s], xt = xur[s];
            int tl = t + SPF < SCAN_T ? t + SPF : SCAN_T - 1;
            Br[s][0] = *(const uint4*)(pB + (size_t)tl * OPAD);
            Br[s][1] = *(const uint4*)(pB + (size_t)tl * OPAD + 8);
            dtr[s] = dtp[(size_t)tl * DI];
            xur[s] = bf2f(pU[(size_t)tl * OPAD]);
            float uv = cbv;
            uv = fmaf(cw0, x3, uv);
            uv = fmaf(cw1, x2, uv);
            uv = fmaf(cw2, x1, uv);
            uv = fmaf(cw3, xt, uv);
            x3 = x2; x2 = x1; x1 = xt;
            float Bf[16];
            unpack8(b0, Bf); unpack8(b1, Bf + 8);
            float dtu = dtv * uv;
            #pragma unroll
            for (int n = 0; n < 16; ++n) {
                float dA = __expf(dtv * a[n]);
                h[n] = fmaf(dA, h[n], dtu * Bf[n]);
                Av[n] *= dA;
            }
        }
    }
    size_t o = (((size_t)c * 2 + b) * 1536 + d) * 16;
    #pragma unroll
    for (int k = 0; k < 4; ++k) {
        *(float4*)(chkA + o + k * 4) = make_float4(Av[4*k], Av[4*k+1], Av[4*k+2], Av[4*k+3]);
        *(float4*)(chkB + o + k * 4) = make_float4(h[4*k], h[4*k+1], h[4*k+2], h[4*k+3]);
    }
}

// ---------------- scan v3 pass 2: fold chunk summaries -> h_start ------------
// One thread per (b,d,n): 49152 threads / 192 blocks.
__global__ void __launch_bounds__(256) scan_comb_kernel(const float* __restrict__ chkA,
        const float* __restrict__ chkB, float* __restrict__ hstart) {
    int idx = blockIdx.x * 256 + threadIdx.x;  // b*24576 + d*16 + n
    float hs = 0.f;
    for (int c = 0; c < SCAN_P; ++c) {
        size_t o = (size_t)c * 49152 + idx;
        hstart[o] = hs;
        hs = fmaf(chkA[o], hs, chkB[o]);
    }
}

// ---------------- scan v3 pass 3: replay with h_start, emit y; conv fused ----
__global__ void __launch_bounds__(256, 2) scan2_kernel(const u16* __restrict__ p,
        const float* __restrict__ dt, const float* __restrict__ A_log,
        const float* __restrict__ cw, const float* __restrict__ cb,
        const float* __restrict__ Dskip,
        const float* __restrict__ hstart, float* __restrict__ y) {
    int d = blockIdx.x * 256 + threadIdx.x;
    int b = blockIdx.y, c = blockIdx.z;
    int t0base = c * SCAN_T;
    float a[16];
    #pragma unroll
    for (int n = 0; n < 16; ++n) a[n] = -__expf(A_log[d * 16 + n]);
    float Dsk = Dskip[d];
    float cw0 = cw[d*4], cw1 = cw[d*4+1], cw2 = cw[d*4+2], cw3 = cw[d*4+3];
    float cbv = cb[d];
    const u16* pB = p + (size_t)(b * 1024 + t0base) * OPAD + B0 + d * 16;
    const u16* pC = p + (size_t)(b * 1024 + t0base) * OPAD + C0 + d * 16;
    const u16* pU = p + (size_t)(b * 1024 + t0base) * OPAD + U0 + d;
    const float* dtp = dt + (size_t)(b * 1024 + t0base) * DI + d;
    float* yp        = y  + (size_t)(b * 1024 + t0base) * DI + d;
    float x1, x2, x3;
    if (c == 0) { x1 = x2 = x3 = 0.f; }
    else {
        x1 = bf2f(*(pU - (long)OPAD));
        x2 = bf2f(*(pU - 2L * OPAD));
        x3 = bf2f(*(pU - 3L * OPAD));
    }
    uint4 Br[SPF][2], Cr[SPF][2]; float dtr[SPF], xur[SPF];
    #pragma unroll
    for (int i = 0; i < SPF; ++i) {
        Br[i][0] = *(const uint4*)(pB + (size_t)i * OPAD);
        Br[i][1] = *(const uint4*)(pB + (size_t)i * OPAD + 8);
        Cr[i][0] = *(const uint4*)(pC + (size_t)i * OPAD);
        Cr[i][1] = *(const uint4*)(pC + (size_t)i * OPAD + 8);
        dtr[i] = dtp[(size_t)i * DI];
        xur[i] = bf2f(pU[(size_t)i * OPAD]);
    }
    float h[16];
    {
        size_t o = ((size_t)c * 3072 + (size_t)b * 1536 + d) * 16;
        #pragma unroll
        for (int k = 0; k < 4; ++k) {
            float4 hv = *(const float4*)(hstart + o + k * 4);
            h[4*k] = hv.x; h[4*k+1] = hv.y; h[4*k+2] = hv.z; h[4*k+3] = hv.w;
        }
    }
    for (int t0 = 0; t0 < SCAN_T; t0 += SPF) {
        #pragma unroll
        for (int s = 0; s < SPF; ++s) {
            int t = t0 + s;
            uint4 b0 = Br[s][0], b1 = Br[s][1], c0 = Cr[s][0], c1 = Cr[s][1];
            float dtv = dtr[s], xt = xur[s];
            int tl = t + SPF < SCAN_T ? t + SPF : SCAN_T - 1;
            Br[s][0] = *(const uint4*)(pB + (size_t)tl * OPAD);
            Br[s][1] = *(const uint4*)(pB + (size_t)tl * OPAD + 8);
            Cr[s][0] = *(const uint4*)(pC + (size_t)tl * OPAD);
            Cr[s][1] = *(const uint4*)(pC + (size_t)tl * OPAD + 8);
            dtr[s] = dtp[(size_t)tl * DI];
            xur[s] = bf2f(pU[(size_t)tl * OPAD]);
            float uv = cbv;
            uv = fmaf(cw0, x3, uv);
            uv = fmaf(cw1, x2, uv);
            uv = fmaf(cw2, x1, uv);
            uv = fmaf(cw3, xt, uv);
            x3 = x2; x2 = x1; x1 = xt;
            float Bf[16], Cf[16];
            unpack8(b0, Bf); unpack8(b1, Bf + 8);
            unpack8(c0, Cf); unpack8(c1, Cf + 8);
            float dtu = dtv * uv;
            #pragma unroll
            for (int n = 0; n < 16; ++n) {
                float dA = __expf(dtv * a[n]);
                h[n] = fmaf(dA, h[n], dtu * Bf[n]);
            }
            float a0 = fmaf(Cf[0], h[0], uv * Dsk), a1 = Cf[1] * h[1];
            float a2 = Cf[2] * h[2], a3 = Cf[3] * h[3];
            #pragma unroll
            for (int n = 4; n < 16; n += 4) {
                a0 = fmaf(Cf[n],   h[n],   a0);
                a1 = fmaf(Cf[n+1], h[n+1], a1);
                a2 = fmaf(Cf[n+2], h[n+2], a2);
                a3 = fmaf(Cf[n+3], h[n+3], a3);
            }
            yp[(size_t)t * DI] = (a0 + a1) + (a2 + a3);
        }
    }
}

// ---------------- gating + RMSNorm + residual -> g (bf16) --------------------
__global__ void __launch_bounds__(256) gate_kernel(const u16* __restrict__ p,
        const float* __restrict__ y, const float* __restrict__ res,
        const float* __restrict__ norm_w, u16* __restrict__ g) {
    int m = blockIdx.x, tid = threadIdx.x;
    const u16* pz = p + (size_t)m * OPAD + Z0;
    const float* yr = y + (size_t)m * DI;
    float gp[6];
    float ss = 0.f, dummy = 0.f;
    #pragma unroll
    for (int i = 0; i < 6; ++i) {
        int d = i * 256 + tid;
        float z = bf2f(pz[d]);
        float gv = yr[d] * z / (1.f + __expf(-z));
        gp[i] = gv;
        ss += gv * gv;
    }
    block_reduce2(ss, dummy);
    float scale = rsqrtf(ss * (1.f / DI) + 1e-6f);
    #pragma unroll
    for (int i = 0; i < 6; ++i) {
        int d = i * 256 + tid;
        float val = gp[i] * scale * norm_w[d] + res[(size_t)m * DI + d];
        g[(size_t)m * DI + d] = f2bf(val);
    }
}

// ---------------- host ----------------
extern "C" void kernel_launch(void* const* d_in, const int* in_sizes, int n_in,
                              void* d_out, int out_size, void* d_ws, size_t ws_size,
                              hipStream_t stream) {
    const float* x       = (const float*)d_in[0];
    const float* ln_w    = (const float*)d_in[1];
    const float* ln_b    = (const float*)d_in[2];
    const float* W_in    = (const float*)d_in[3];
    const float* W_dt    = (const float*)d_in[4];
    const float* conv_w  = (const float*)d_in[5];
    const float* conv_b  = (const float*)d_in[6];
    const float* A_log   = (const float*)d_in[7];
    const float* Dskip   = (const float*)d_in[8];
    const float* dt_bias = (const float*)d_in[9];
    const float* norm_w  = (const float*)d_in[10];
    const float* W_res   = (const float*)d_in[11];
    const float* W_out   = (const float*)d_in[12];
    float* out = (float*)d_out;

    char* wsb = (char*)d_ws;
    u16* Wbf     = (u16*)(wsb + 0);           //  80,609,280  (OPAD*768*2)
    u16* Wresbf  = (u16*)(wsb + 80609280);    //   2,359,296
    u16* Woutbf  = (u16*)(wsb + 82968576);    //   2,359,296
    u16* xnbf    = (u16*)(wsb + 85327872);    //   3,145,728
    u16* xbf     = (u16*)(wsb + 88473600);    //   3,145,728
    u16* pbuf    = (u16*)(wsb + 91619328);    // 214,958,080  (2048*OPAD*2)
    float* dtv   = (float*)(wsb + 319160320); //  12,582,912
    float* ybuf  = (float*)(wsb + 331743232); //  12,582,912
    float* resb  = (float*)(wsb + 344326144); //  12,582,912
    u16* gbuf    = (u16*)(wsb + 356909056);   //   6,291,456  -> total 363,200,512
    // scan chunk buffers alias the Wbf region (dead after gemm1):
    float* chkA  = (float*)(wsb + 0);         //  12,582,912 (64*2*1536*16*4)
    float* chkB  = (float*)(wsb + 12582912);  //  12,582,912
    float* hst   = (float*)(wsb + 25165824);  //  12,582,912 (ends 37.7MB < 80.6MB)

    // 1) weight converts
    cvt_kernel<<<39360, 256, 0, stream>>>(W_in, Wbf, (long)OTOT * DM, (long)OPAD * DM);
    cvt_kernel<<<1152, 256, 0, stream>>>(W_res, Wresbf, (long)DI * DM, (long)DI * DM);
    cvt_kernel<<<1152, 256, 0, stream>>>(W_out, Woutbf, (long)DM * DI, (long)DM * DI);
    // 2) layernorm
    ln_kernel<<<2048, 256, 0, stream>>>(x, ln_w, ln_b, xnbf, xbf);
    // 3) big GEMM: p = xn @ W_in^T (bf16 out, ldc = OPAD); 256^2 2-phase/tile
    gemm256_bt<<<dim3(8, 205), 512, 0, stream>>>(xnbf, Wbf, pbuf, DM, OPAD);
    // 4) res = x @ W_res^T (f32 out)
    gemm_bt<0><<<dim3(16, 12), 256, 0, stream>>>(xbf, Wresbf, resb, DM, DI);
    // 5) dt
    dt_kernel<<<512, 256, 0, stream>>>(pbuf, W_dt, dt_bias, dtv);
    // 6) scan v3: chunk-parallel, lane-owns-d, conv fused
    scan1_kernel<<<dim3(6, 2, SCAN_P), 256, 0, stream>>>(pbuf, dtv, A_log, conv_w, conv_b, chkA, chkB);
    scan_comb_kernel<<<192, 256, 0, stream>>>(chkA, chkB, hst);
    scan2_kernel<<<dim3(6, 2, SCAN_P), 256, 0, stream>>>(pbuf, dtv, A_log, conv_w, conv_b, Dskip, hst, ybuf);
    // 7) gate + rmsnorm + residual
    gate_kernel<<<2048, 256, 0, stream>>>(pbuf, ybuf, resb, norm_w, gbuf);
    // 8) out = g @ W_out^T (f32 out)
    gemm_bt<0><<<dim3(16, 6), 256, 0, stream>>>(gbuf, Woutbf, out, DI, DM);
}